// Round 1
// baseline (151.414 us; speedup 1.0000x reference)
//
#include <hip/hip_runtime.h>
#include <hip/hip_bf16.h>

// Problem constants (fixed by reference): B=512, F=8, D=4, R=32, U=64
#define NB 512
#define NF 8
#define ND 4
#define NR 32
#define NU 64
#define G  4   // batches (b) per wave per h-step

typedef float f32x4 __attribute__((ext_vector_type(4)));
typedef float f32x2 __attribute__((ext_vector_type(2)));
typedef short s16x8 __attribute__((ext_vector_type(8)));
typedef unsigned u32x4 __attribute__((ext_vector_type(4)));

// ---- packed fp32 math, inline asm (PROVEN R3-R10; opaque to the optimizer
// -- R9 showed native f32x2 ops get reassociated and break the chain
// numerics). *_s variants take the wave-uniform x operand as an SGPR pair
// ("s" constraint) -- VOP3P permits one SGPR source (PROVEN R11: freed 32
// VGPRs of broadcast duplicates, killed the spills). Values bit-identical.
__device__ inline f32x2 pk_mul_s(f32x2 a, f32x2 s) {
    f32x2 d;
    asm("v_pk_mul_f32 %0, %1, %2" : "=v"(d) : "v"(a), "s"(s));
    return d;
}
__device__ inline f32x2 pk_fma_s(f32x2 a, f32x2 s, f32x2 c) {
    f32x2 d;
    asm("v_pk_fma_f32 %0, %1, %2, %3" : "=v"(d) : "v"(a), "s"(s), "v"(c));
    return d;
}

// fp32 pair -> packed bf16 (lo = first arg). Builtin proven R6-R10 (absmax
// 0.25 across validation + graph replays). Fallback: R4-proven 3-op RNU.
__device__ inline unsigned cvt_pk(float lo, float hi) {
#if __has_builtin(__builtin_amdgcn_cvt_pk_bf16_f32)
    auto r = __builtin_amdgcn_cvt_pk_bf16_f32(lo, hi);
    static_assert(sizeof(r) == 4, "cvt_pk_bf16 return must be 32-bit");
    return __builtin_bit_cast(unsigned, r);
#else
    unsigned ul = __float_as_uint(lo) + 0x8000u;
    unsigned uh = __float_as_uint(hi) + 0x8000u;
    return __builtin_amdgcn_perm(uh, ul, 0x07060302u);
#endif
}

// wave-uniform float -> SGPR float (readfirstlane; value unchanged)
__device__ inline float rfl(float v) {
    return __builtin_bit_cast(float, __builtin_amdgcn_readfirstlane(
                                         __builtin_bit_cast(int, v)));
}

// ---------------------------------------------------------------------------
// Pre-pass: K[d][i][j][f][u] -> K3, pair-interleaved:
//   K3 float index = (u*8+f)*4096 + (q*4+jp)*256 + ((I*16+c)*4 + d)*2 + par
// where e = 256q + 64jp + 32par + 16I + c. Unchanged since R3 (proven).
// ---------------------------------------------------------------------------
__global__ __launch_bounds__(256) void tr_k3(const float* __restrict__ K,
                                             float* __restrict__ K3) {
    __shared__ float lds[256 * 36];   // rows (d*64+s) x 32 u, pad to 36
    const int t   = threadIdx.x;
    const int bid = blockIdx.x;
    const int uh = bid & 1, jp = (bid >> 1) & 3, q = (bid >> 3) & 3, f = bid >> 5;
    const int u0 = uh * 32;

    {   // read phase: rows r = d*64 + s, 32 floats of u each
        const int rr = t >> 3, col4 = (t & 7) * 4;
#pragma unroll
        for (int i = 0; i < 8; ++i) {
            int r = i * 32 + rr;              // 0..255
            int d = r >> 6, s = r & 63;
            int e = q * 256 + jp * 64 + s;
            f32x4 v = *(const f32x4*)(K + ((size_t)((d << 10) + e) << 9)
                                        + (f << 6) + u0 + col4);
            *(f32x4*)(lds + r * 36 + col4) = v;
        }
    }
    __syncthreads();
    {   // write phase: per u_l, 256 consecutive floats; 128B-coalesced runs
        const int u_l = t >> 3, lane8 = t & 7;
        float* dst = K3 + ((size_t)((u0 + u_l) * 8 + f) << 12) + (q * 4 + jp) * 256;
#pragma unroll
        for (int g2 = 0; g2 < 8; ++g2) {
            int idx4 = lane8 + g2 * 8;        // 0..63
            int dh = idx4 & 1, Ic = idx4 >> 1;  // Ic = I*16+c in 0..31
            int d0 = dh * 2;
            f32x4 v;
            v[0] = lds[(d0 * 64 + 0  + Ic) * 36 + u_l];
            v[1] = lds[(d0 * 64 + 32 + Ic) * 36 + u_l];
            v[2] = lds[((d0 + 1) * 64 + 0  + Ic) * 36 + u_l];
            v[3] = lds[((d0 + 1) * 64 + 32 + Ic) * 36 + u_l];
            *(f32x4*)(dst + idx4 * 4) = v;
        }
    }
}

// ---------------------------------------------------------------------------
// Main. R12 theory: R11 (green, main dispatch 61.3us) is VALU-bound at only
// 33% occupancy -- 16 blocks/CU of work vs ~8-block residency gives two
// rounds + drain tail, and waves_per_eu(4,4)'s max side discourages
// residency. Single change: grid 4096 -> 2048 with an outer h-loop (each
// wave runs TWO bgroup chains sequentially, reusing its wave-private LDS
// state buffers -- DS pipe is in-order per wave, fence already in place),
// and waves_per_eu(4,4) -> (4) (keep the <=64-VGPR budget, drop the cap).
// 2048 blocks = exactly 8/CU resident (LDS ceiling is 10) -> single round.
// Per-(b,u) arithmetic bit-identical to R11.
// Discriminators: Occupancy 33 -> ~50, VALUBusy 65 -> ~85-90,
// main dur 61 -> ~43-47us, absmax exactly 0.25, FETCH/WRITE/conflicts flat.
// All else per R10/R11: jp-outer/g-inner dots, u-minor mapping, builtin cvt,
// wave-private N-buffers, SGPR xq broadcasts, fence per f, f-loop unrolled.
// ---------------------------------------------------------------------------
__global__ __launch_bounds__(128)
__attribute__((amdgpu_waves_per_eu(4)))
void tr_main12(const float* __restrict__ X,
               const float* __restrict__ K3,
               float* __restrict__ out) {
    const int tid  = threadIdx.x;
    const int w    = __builtin_amdgcn_readfirstlane(tid >> 6);  // wave id, SGPR
    const int lane = tid & 63;
    const int c    = lane & 15;
    const int q    = lane >> 4;
    const int u    = blockIdx.x & 63;                 // u-minor (R3/R7-proven)
    const int bg2  = blockIdx.x >> 6;                 // 0..31 (two bgroups each)

    __shared__ __attribute__((aligned(16))) char lds[2 * G * 2048];
    char* Nb0 = lds + w * (G * 2048);

    // identity B-frags for f=0: B[k=8q+j][n=c(+16)]
    s16x8 idf0, idf1;
#pragma unroll
    for (int jj = 0; jj < 8; ++jj) {
        idf0[jj] = (short)((8 * q + jj == c) ? 0x3F80 : 0);
        idf1[jj] = (short)((8 * q + jj == 16 + c) ? 0x3F80 : 0);
    }

    const float* Kt = K3 + ((size_t)u << 15) + (q << 10) + (c << 3);
    const f32x4 z = {0.f, 0.f, 0.f, 0.f};

#pragma unroll 1
    for (int h = 0; h < 2; ++h) {
        const int b0 = ((((bg2 << 1) + h) << 1) + w) * G;   // SGPR-computed

#pragma unroll
        for (int f = 0; f < NF; ++f) {
            const float* Kf = Kt + (f << 12);

            // ---- X broadcasts -> SGPR pairs (wave-uniform) ----
            f32x2 xq[G][4];
#pragma unroll
            for (int g = 0; g < G; ++g) {
                const f32x4 xv = *(const f32x4*)(X + ((b0 + g) << 5) + (f << 2));
#pragma unroll
                for (int d = 0; d < 4; ++d) {
                    float sx = rfl(xv[d]);
                    xq[g][d] = (f32x2){sx, sx};
                }
            }

            // ---- A-phase: jp-outer, g-inner; 1-deep staging prefetch ----
            u32x4 A0u[G], A1u[G];
            f32x4 sv0 = *(const f32x4*)(Kf + 0);      // (jp, I=0) d0d1 pairs
            f32x4 sw0 = *(const f32x4*)(Kf + 4);      // (jp, I=0) d2d3 pairs
            f32x4 sv1 = *(const f32x4*)(Kf + 128);    // (jp, I=1) d0d1
            f32x4 sw1 = *(const f32x4*)(Kf + 132);    // (jp, I=1) d2d3
#pragma unroll
            for (int jp = 0; jp < 4; ++jp) {
                f32x4 cv0 = sv0, cw0 = sw0, cv1 = sv1, cw1 = sw1;
                if (jp < 3) {
                    const float* pn = Kf + ((jp + 1) << 8);
                    sv0 = *(const f32x4*)(pn + 0);
                    sw0 = *(const f32x4*)(pn + 4);
                    sv1 = *(const f32x4*)(pn + 128);
                    sw1 = *(const f32x4*)(pn + 132);
                }
#pragma unroll
                for (int g = 0; g < G; ++g) {
                    {   // I = 0
                        f32x2 p0 = {cv0[0], cv0[1]}, p1 = {cv0[2], cv0[3]};
                        f32x2 p2 = {cw0[0], cw0[1]}, p3 = {cw0[2], cw0[3]};
                        f32x2 tv = pk_mul_s(p0, xq[g][0]);
                        tv = pk_fma_s(p1, xq[g][1], tv);
                        tv = pk_fma_s(p2, xq[g][2], tv);
                        tv = pk_fma_s(p3, xq[g][3], tv);
                        A0u[g][jp] = cvt_pk(tv[0], tv[1]);
                    }
                    {   // I = 1
                        f32x2 p0 = {cv1[0], cv1[1]}, p1 = {cv1[2], cv1[3]};
                        f32x2 p2 = {cw1[0], cw1[1]}, p3 = {cw1[2], cw1[3]};
                        f32x2 tv = pk_mul_s(p0, xq[g][0]);
                        tv = pk_fma_s(p1, xq[g][1], tv);
                        tv = pk_fma_s(p2, xq[g][2], tv);
                        tv = pk_fma_s(p3, xq[g][3], tv);
                        A1u[g][jp] = cvt_pk(tv[0], tv[1]);
                    }
                }
            }

            // ---- MFMA phase per g ----
#pragma unroll
            for (int g = 0; g < G; ++g) {
                char* nb = Nb0 + (g << 11);
                s16x8 A0 = __builtin_bit_cast(s16x8, A0u[g]);
                s16x8 A1 = __builtin_bit_cast(s16x8, A1u[g]);

                s16x8 bf0, bf1;
                if (f == 0) { bf0 = idf0; bf1 = idf1; }
                else {
                    bf0 = *(const s16x8*)(nb + (((q << 5) | c) << 4));
                    bf1 = *(const s16x8*)(nb + (((q << 5) | c) << 4) + 256);
                }

                if (f < NF - 1) {
                    f32x4 c00 = __builtin_amdgcn_mfma_f32_16x16x32_bf16(A0, bf0, z, 0, 0, 0);
                    f32x4 c01 = __builtin_amdgcn_mfma_f32_16x16x32_bf16(A0, bf1, z, 0, 0, 0);
                    f32x4 c10 = __builtin_amdgcn_mfma_f32_16x16x32_bf16(A1, bf0, z, 0, 0, 0);
                    f32x4 c11 = __builtin_amdgcn_mfma_f32_16x16x32_bf16(A1, bf1, z, 0, 0, 0);
                    // writeback N' (bf16) for next f
#pragma unroll
                    for (int I = 0; I < 2; ++I)
#pragma unroll
                        for (int J = 0; J < 2; ++J) {
                            f32x4 a = (I == 0) ? (J == 0 ? c00 : c01)
                                               : (J == 0 ? c10 : c11);
                            unsigned lo = cvt_pk(a[0], a[1]);
                            unsigned hi = cvt_pk(a[2], a[3]);
                            uint2 val; val.x = lo; val.y = hi;
                            // slot(p = 2I + (q>>1), n = 16J + c), byte +8*(q&1)
                            *(uint2*)(nb + (((((I << 1) | (q >> 1)) << 5) | (J << 4) | c) << 4)
                                         + ((q & 1) << 3)) = val;
                        }
                } else {
                    // last step: only diagonal tiles feed the trace
                    f32x4 c00 = __builtin_amdgcn_mfma_f32_16x16x32_bf16(A0, bf0, z, 0, 0, 0);
                    f32x4 c11 = __builtin_amdgcn_mfma_f32_16x16x32_bf16(A1, bf1, z, 0, 0, 0);
                    f32x4 t4 = c00 + c11;
                    int ri = c & 3;
                    float s = (ri == 0) ? t4[0] : (ri == 1) ? t4[1]
                            : (ri == 2) ? t4[2] : t4[3];
                    s = ((c >> 2) == q) ? s : 0.f;
#pragma unroll
                    for (int m = 32; m >= 1; m >>= 1) s += __shfl_xor(s, m, 64);
                    if (lane == 0) out[((b0 + g) << 6) + u] = s;
                }
            }
            // Compiler memory fence: this-f LDS writes must precede next-f
            // (and next-h f=0) LDS reads in program order (HW DS pipe is
            // in-order per wave; only the compiler could break it). Zero
            // instructions emitted. Also orders h=0/f=7 reads before h=1/f=0
            // writeback into the same wave-private buffers.
            asm volatile("" ::: "memory");
        }
    }
}

extern "C" void kernel_launch(void* const* d_in, const int* in_sizes, int n_in,
                              void* d_out, int out_size, void* d_ws, size_t ws_size,
                              hipStream_t stream) {
    (void)in_sizes; (void)n_in; (void)out_size; (void)ws_size;
    const float* X = (const float*)d_in[0];   // [512][8][4]
    const float* K = (const float*)d_in[1];   // [4][32][32][8][64]
    float* out = (float*)d_out;               // [512][64]
    float* K3 = (float*)d_ws;                 // 8 MB, pair-interleaved

    hipLaunchKernelGGL(tr_k3, dim3(256), dim3(256), 0, stream, K, K3);
    hipLaunchKernelGGL(tr_main12, dim3(2048), dim3(128), 0, stream, X, K3, out);
}

// Round 4
// 95.432 us; speedup vs baseline: 1.5866x; 1.5866x over previous
//
#include <hip/hip_runtime.h>
#include <hip/hip_fp16.h>

// Problem constants (fixed by reference): B=512, F=8, D=4, R=32, U=64
#define NB 512
#define NF 8
#define ND 4
#define NR 32
#define NU 64
#define G  4   // batches (b) per wave

typedef float f32x4 __attribute__((ext_vector_type(4)));
typedef unsigned u32x4 __attribute__((ext_vector_type(4)));
typedef _Float16 f16x8 __attribute__((ext_vector_type(8)));

// ---- R14/R15: A-phase in packed f16. v_pk_mul_f16/v_pk_fma_f16 are the
// SAME VOP3P family as the R3-R11-proven pk_fma_f32 asm (one SGPR source
// allowed; "s" constraint proven R11), but FULL-rate (2cy vs 4cy) and they
// produce the packed 16-bit A-word directly (no cvt_pk needed). R13's
// v_dot2_f32_f16 path is ABANDONED (nondeterministic wrong results on
// gfx950; never proven). Asm opaque to optimizer (R9: native vector ops
// get reassociated and break chain numerics).
// (R15 = R14 resubmitted verbatim: R14's bench died to an infra error
// before compiling anything; no kernel signal was obtained.)
__device__ inline unsigned pkmul_h(unsigned a, unsigned s) {
    unsigned d;
    asm("v_pk_mul_f16 %0, %1, %2" : "=v"(d) : "v"(a), "s"(s));
    return d;
}
__device__ inline unsigned pkfma_h(unsigned a, unsigned s, unsigned c) {
    unsigned d;
    asm("v_pk_fma_f16 %0, %1, %2, %3" : "=v"(d) : "v"(a), "s"(s), "v"(c));
    return d;
}

// f32 pair -> packed f16 word, RTZ, single instruction (v_cvt_pkrtz_f16_f32).
// lo = first arg. Used for N' writeback and X broadcast (precision budget:
// f16 RTZ rel 2^-10, vs the old bf16 chain's 2^-8 RNE -- strictly better).
__device__ inline unsigned pkrtz(float a, float b) {
    auto h = __builtin_amdgcn_cvt_pkrtz(a, b);
    static_assert(sizeof(h) == 4, "cvt_pkrtz must return 32-bit");
    return __builtin_bit_cast(unsigned, h);
}

// f32 pair -> packed f16 word, RNE (pre-pass only; K deserves round-nearest)
__device__ inline unsigned h2pack(float a, float b) {
    unsigned ha = (unsigned)__half_as_ushort(__float2half(a));
    unsigned hb = (unsigned)__half_as_ushort(__float2half(b));
    return ha | (hb << 16);
}

// wave-uniform u32 -> SGPR (readfirstlane; value unchanged)
__device__ inline unsigned rfl_u(unsigned v) {
    return (unsigned)__builtin_amdgcn_readfirstlane((int)v);
}

// ---------------------------------------------------------------------------
// Pre-pass: K[d][i][j][f][u] -> K3h, f16 par-pair words. EXACT R3-proven
// gather; only the emit packs the (par0,par1) float pair into one f16 word:
//   K3h u32 index = (u*8+f)*2048 + (q*4+jp)*128 + (I*16+c)*4 + d
//   word = half2( K[d][e_par0], K[d][e_par1] ),  e = 256q+64jp+32par+16I+c
// (This is the R3/R11 f32 layout with the trailing par dimension packed.)
// ---------------------------------------------------------------------------
__global__ __launch_bounds__(256) void tr_k3h(const float* __restrict__ K,
                                              unsigned* __restrict__ K3h) {
    __shared__ float lds[256 * 36];   // rows (d*64+s) x 32 u, pad to 36
    const int t   = threadIdx.x;
    const int bid = blockIdx.x;
    const int uh = bid & 1, jp = (bid >> 1) & 3, q = (bid >> 3) & 3, f = bid >> 5;
    const int u0 = uh * 32;

    {   // read phase: rows r = d*64 + s, 32 floats of u each (UNCHANGED R3)
        const int rr = t >> 3, col4 = (t & 7) * 4;
#pragma unroll
        for (int i = 0; i < 8; ++i) {
            int r = i * 32 + rr;              // 0..255
            int d = r >> 6, s = r & 63;
            int e = q * 256 + jp * 64 + s;
            f32x4 v = *(const f32x4*)(K + ((size_t)((d << 10) + e) << 9)
                                        + (f << 6) + u0 + col4);
            *(f32x4*)(lds + r * 36 + col4) = v;
        }
    }
    __syncthreads();
    {   // write phase: R3 gather, f16-pair emit (8B per thread-iter)
        const int u_l = t >> 3, lane8 = t & 7;
        unsigned* dst = K3h + ((size_t)((u0 + u_l) * 8 + f) << 11)
                            + ((q * 4 + jp) << 7);
#pragma unroll
        for (int g2 = 0; g2 < 8; ++g2) {
            int idx4 = lane8 + g2 * 8;        // 0..63
            int dh = idx4 & 1, Ic = idx4 >> 1;  // Ic = I*16+c in 0..31
            int d0 = dh * 2;
            float v0 = lds[(d0 * 64 + 0  + Ic) * 36 + u_l];   // d0, par0
            float v1 = lds[(d0 * 64 + 32 + Ic) * 36 + u_l];   // d0, par1
            float v2 = lds[((d0 + 1) * 64 + 0  + Ic) * 36 + u_l];
            float v3 = lds[((d0 + 1) * 64 + 32 + Ic) * 36 + u_l];
            uint2 wv; wv.x = h2pack(v0, v1); wv.y = h2pack(v2, v3);
            *(uint2*)(dst + idx4 * 2) = wv;   // words (Ic*4+2dh), (+1)
        }
    }
}

// ---------------------------------------------------------------------------
// Main. R11 structure EXACTLY (grid 4096, no h-loop, waves_per_eu(4,4) --
// R12 proved the h-loop busts the 64-VGPR budget and spills 107MB). R14/R15
// single concept: the whole chain runs in f16 instead of bf16.
//   A-phase: 4x v_pk_{mul,fma}_f16 per A-word (full-rate 2cy, SGPR x
//            broadcast), NO cvt -- per-wave-per-f 576cy -> 256cy.
//   MFMA: mfma_f32_16x16x32_f16 (fragment layout identical to bf16).
//   N' writeback: v_cvt_pkrtz_f16_f32 (same instr count as before).
// Discriminators: absmax ~0.01-0.1 (f16 more precise than bf16 chain),
// main dur 61 -> ~40-46us, VALUBusy 65 -> ~50-57, FETCH 4839 -> ~2700KB,
// WRITE_SIZE ~1MB (no spills), VGPR <= 52.
// All else per R11: jp-outer/g-inner, u-minor mapping, wave-private
// N-buffers, fence per f, f-loop unrolled.
// ---------------------------------------------------------------------------
__global__ __launch_bounds__(128)
__attribute__((amdgpu_waves_per_eu(4, 4)))
void tr_main14(const float* __restrict__ X,
               const unsigned* __restrict__ K3h,
               float* __restrict__ out) {
    const int tid  = threadIdx.x;
    const int w    = __builtin_amdgcn_readfirstlane(tid >> 6);  // wave id, SGPR
    const int lane = tid & 63;
    const int c    = lane & 15;
    const int q    = lane >> 4;
    const int u      = blockIdx.x & 63;               // u-minor (R3/R7-proven)
    const int bgroup = blockIdx.x >> 6;               // 0..63
    const int b0     = ((bgroup << 1) + w) * G;       // SGPR-computed

    __shared__ __attribute__((aligned(16))) char lds[2 * G * 2048];
    char* Nb0 = lds + w * (G * 2048);

    // identity B-frags for f=0: B[k=8q+j][n=c(+16)]; f16 1.0 = 0x3C00 exact
    f16x8 idf0, idf1;
#pragma unroll
    for (int jj = 0; jj < 8; ++jj) {
        idf0[jj] = (8 * q + jj == c) ? (_Float16)1.0f : (_Float16)0.0f;
        idf1[jj] = (8 * q + jj == 16 + c) ? (_Float16)1.0f : (_Float16)0.0f;
    }

    const unsigned* Kt = K3h + ((size_t)u << 14) + (q << 9) + (c << 2);
    const f32x4 z = {0.f, 0.f, 0.f, 0.f};

#pragma unroll
    for (int f = 0; f < NF; ++f) {
        const unsigned* Kf = Kt + (f << 11);

        // ---- X broadcasts -> packed (x_d,x_d) f16 words in SGPRs ----
        unsigned xdd[G][4];
#pragma unroll
        for (int g = 0; g < G; ++g) {
            const f32x4 xv = *(const f32x4*)(X + ((b0 + g) << 5) + (f << 2));
#pragma unroll
            for (int d = 0; d < 4; ++d)
                xdd[g][d] = rfl_u(pkrtz(xv[d], xv[d]));
        }

        // ---- A-phase: jp-outer, g-inner; 1-deep staging prefetch ----
        // One u32x4 load per (jp,I) = the 4 d-words for this lane's (I,c).
        u32x4 A0u[G], A1u[G];
        u32x4 s0 = *(const u32x4*)(Kf + 0);       // (jp=0, I=0)
        u32x4 s1 = *(const u32x4*)(Kf + 64);      // (jp=0, I=1)
#pragma unroll
        for (int jp = 0; jp < 4; ++jp) {
            u32x4 c0 = s0, c1 = s1;
            if (jp < 3) {
                const unsigned* pn = Kf + ((jp + 1) << 7);
                s0 = *(const u32x4*)(pn + 0);
                s1 = *(const u32x4*)(pn + 64);
            }
#pragma unroll
            for (int g = 0; g < G; ++g) {
                {   // I = 0: A-word = (T[e_par0], T[e_par1]) f16
                    unsigned tv = pkmul_h(c0[0], xdd[g][0]);
                    tv = pkfma_h(c0[1], xdd[g][1], tv);
                    tv = pkfma_h(c0[2], xdd[g][2], tv);
                    tv = pkfma_h(c0[3], xdd[g][3], tv);
                    A0u[g][jp] = tv;
                }
                {   // I = 1
                    unsigned tv = pkmul_h(c1[0], xdd[g][0]);
                    tv = pkfma_h(c1[1], xdd[g][1], tv);
                    tv = pkfma_h(c1[2], xdd[g][2], tv);
                    tv = pkfma_h(c1[3], xdd[g][3], tv);
                    A1u[g][jp] = tv;
                }
            }
        }

        // ---- MFMA phase per g (R11 structure; f16 MFMA, same layout) ----
#pragma unroll
        for (int g = 0; g < G; ++g) {
            char* nb = Nb0 + (g << 11);
            f16x8 A0 = __builtin_bit_cast(f16x8, A0u[g]);
            f16x8 A1 = __builtin_bit_cast(f16x8, A1u[g]);

            f16x8 bf0, bf1;
            if (f == 0) { bf0 = idf0; bf1 = idf1; }
            else {
                bf0 = *(const f16x8*)(nb + (((q << 5) | c) << 4));
                bf1 = *(const f16x8*)(nb + (((q << 5) | c) << 4) + 256);
            }

            if (f < NF - 1) {
                f32x4 c00 = __builtin_amdgcn_mfma_f32_16x16x32_f16(A0, bf0, z, 0, 0, 0);
                f32x4 c01 = __builtin_amdgcn_mfma_f32_16x16x32_f16(A0, bf1, z, 0, 0, 0);
                f32x4 c10 = __builtin_amdgcn_mfma_f32_16x16x32_f16(A1, bf0, z, 0, 0, 0);
                f32x4 c11 = __builtin_amdgcn_mfma_f32_16x16x32_f16(A1, bf1, z, 0, 0, 0);
                // writeback N' (f16) for next f
#pragma unroll
                for (int I = 0; I < 2; ++I)
#pragma unroll
                    for (int J = 0; J < 2; ++J) {
                        f32x4 a = (I == 0) ? (J == 0 ? c00 : c01)
                                           : (J == 0 ? c10 : c11);
                        unsigned lo = pkrtz(a[0], a[1]);
                        unsigned hi = pkrtz(a[2], a[3]);
                        uint2 val; val.x = lo; val.y = hi;
                        // slot(p = 2I + (q>>1), n = 16J + c), byte +8*(q&1)
                        *(uint2*)(nb + (((((I << 1) | (q >> 1)) << 5) | (J << 4) | c) << 4)
                                     + ((q & 1) << 3)) = val;
                    }
            } else {
                // last step: only diagonal tiles feed the trace
                f32x4 c00 = __builtin_amdgcn_mfma_f32_16x16x32_f16(A0, bf0, z, 0, 0, 0);
                f32x4 c11 = __builtin_amdgcn_mfma_f32_16x16x32_f16(A1, bf1, z, 0, 0, 0);
                f32x4 t4 = c00 + c11;
                int ri = c & 3;
                float s = (ri == 0) ? t4[0] : (ri == 1) ? t4[1]
                        : (ri == 2) ? t4[2] : t4[3];
                s = ((c >> 2) == q) ? s : 0.f;
#pragma unroll
                for (int m = 32; m >= 1; m >>= 1) s += __shfl_xor(s, m, 64);
                if (lane == 0) out[((b0 + g) << 6) + u] = s;
            }
        }
        // Compiler memory fence: this-f LDS writes must precede next-f LDS
        // reads in program order (HW DS pipe is in-order per wave; only the
        // compiler could break it). Zero instructions emitted.
        asm volatile("" ::: "memory");
    }
}

extern "C" void kernel_launch(void* const* d_in, const int* in_sizes, int n_in,
                              void* d_out, int out_size, void* d_ws, size_t ws_size,
                              hipStream_t stream) {
    (void)in_sizes; (void)n_in; (void)out_size; (void)ws_size;
    const float* X = (const float*)d_in[0];   // [512][8][4]
    const float* K = (const float*)d_in[1];   // [4][32][32][8][64]
    float* out = (float*)d_out;               // [512][64]
    unsigned* K3h = (unsigned*)d_ws;          // 4 MB, f16 par-pair words

    hipLaunchKernelGGL(tr_k3h, dim3(256), dim3(256), 0, stream, K, K3h);
    hipLaunchKernelGGL(tr_main14, dim3(4096), dim3(128), 0, stream, X, K3h, out);
}

// Round 5
// 95.316 us; speedup vs baseline: 1.5886x; 1.0012x over previous
//
#include <hip/hip_runtime.h>
#include <hip/hip_fp16.h>

// Problem constants (fixed by reference): B=512, F=8, D=4, R=32, U=64
#define NB 512
#define NF 8
#define ND 4
#define NR 32
#define NU 64
#define G  4   // batches (b) per wave

typedef float f32x4 __attribute__((ext_vector_type(4)));
typedef unsigned u32x4 __attribute__((ext_vector_type(4)));
typedef _Float16 f16x8 __attribute__((ext_vector_type(8)));

// ---- f16 packed math, inline asm (PROVEN R14/R15: main 61.3 -> 41.8us,
// absmax 0.25). VOP3P one-SGPR-source via "s" constraint (proven R11).
// Asm opaque to optimizer (R9: native vector ops get reassociated).
__device__ inline unsigned pkmul_h(unsigned a, unsigned s) {
    unsigned d;
    asm("v_pk_mul_f16 %0, %1, %2" : "=v"(d) : "v"(a), "s"(s));
    return d;
}
__device__ inline unsigned pkfma_h(unsigned a, unsigned s, unsigned c) {
    unsigned d;
    asm("v_pk_fma_f16 %0, %1, %2, %3" : "=v"(d) : "v"(a), "s"(s), "v"(c));
    return d;
}

// f32 pair -> packed f16 word, RTZ, single instruction (v_cvt_pkrtz_f16_f32).
// lo = first arg. PROVEN R14/R15 for both X broadcast and N' writeback.
__device__ inline unsigned pkrtz(float a, float b) {
    auto h = __builtin_amdgcn_cvt_pkrtz(a, b);
    static_assert(sizeof(h) == 4, "cvt_pkrtz must return 32-bit");
    return __builtin_bit_cast(unsigned, h);
}

// f32 pair -> packed f16 word, RNE (K pre-pass; K deserves round-nearest)
__device__ inline unsigned h2pack(float a, float b) {
    unsigned ha = (unsigned)__half_as_ushort(__float2half(a));
    unsigned hb = (unsigned)__half_as_ushort(__float2half(b));
    return ha | (hb << 16);
}

// ---------------------------------------------------------------------------
// Pre-pass R16: was 256 blocks = 1/CU, latency-bound ~10us. Now 512 blocks
// (u split 32 -> 16 per block; same K3h bytes) + 4 blocks packing X into
// (x_d,x_d) f16 words (same pkrtz op as R15's in-loop broadcast -> same
// bits; main reads them as wave-uniform u32x4, no per-f cvt/rfl).
//   K3h u32 index = (u*8+f)*2048 + (q*4+jp)*128 + (I*16+c)*4 + d
//   word = half2( K[d][e_par0], K[d][e_par1] ),  e = 256q+64jp+32par+16I+c
//   Xh  u32 index = b*32 + f*4 + d;  word = pkrtz(x_bfd, x_bfd)
// ---------------------------------------------------------------------------
__global__ __launch_bounds__(256) void tr_k3h16(const float* __restrict__ K,
                                                const float* __restrict__ X,
                                                unsigned* __restrict__ K3h,
                                                unsigned* __restrict__ Xh) {
    __shared__ float lds[256 * 20];   // rows (d*64+s) x 16 u, pad to 20
    const int t   = threadIdx.x;
    const int bid = blockIdx.x;

    if (bid >= 512) {                 // ---- X-pack blocks (4 x 256) ----
        const int tt = (bid - 512) * 256 + t;     // 0..1023
#pragma unroll
        for (int k = 0; k < 4; ++k) {
            int pair = tt * 4 + k;                // (b,f) pair, 0..4095
            const f32x4 xv = *(const f32x4*)(X + pair * 4);
            u32x4 wv;
#pragma unroll
            for (int d = 0; d < 4; ++d) wv[d] = pkrtz(xv[d], xv[d]);
            *(u32x4*)(Xh + pair * 4) = wv;
        }
        return;
    }

    const int uq = bid & 3, jp = (bid >> 2) & 3, q = (bid >> 4) & 3, f = bid >> 6;
    const int u0 = uq * 16;

    {   // read phase: rows r = d*64 + s, 16 floats of u each
        const int rr = t >> 2, col4 = (t & 3) * 4;
#pragma unroll
        for (int i = 0; i < 4; ++i) {
            int r = i * 64 + rr;              // 0..255
            int d = r >> 6, s = r & 63;
            int e = q * 256 + jp * 64 + s;
            f32x4 v = *(const f32x4*)(K + ((size_t)((d << 10) + e) << 9)
                                        + (f << 6) + u0 + col4);
            *(f32x4*)(lds + r * 20 + col4) = v;
        }
    }
    __syncthreads();
    {   // write phase: per u_l, f16-pair emit (8B per thread-iter)
        const int u_l = t >> 4, lane16 = t & 15;  // u_l 0..15
        unsigned* dst = K3h + ((size_t)((u0 + u_l) * 8 + f) << 11)
                            + ((q * 4 + jp) << 7);
#pragma unroll
        for (int g2 = 0; g2 < 4; ++g2) {
            int idx4 = lane16 + g2 * 16;      // 0..63
            int dh = idx4 & 1, Ic = idx4 >> 1;  // Ic = I*16+c in 0..31
            int d0 = dh * 2;
            float v0 = lds[(d0 * 64 + 0  + Ic) * 20 + u_l];   // d0, par0
            float v1 = lds[(d0 * 64 + 32 + Ic) * 20 + u_l];   // d0, par1
            float v2 = lds[((d0 + 1) * 64 + 0  + Ic) * 20 + u_l];
            float v3 = lds[((d0 + 1) * 64 + 32 + Ic) * 20 + u_l];
            uint2 wv; wv.x = h2pack(v0, v1); wv.y = h2pack(v2, v3);
            *(uint2*)(dst + idx4 * 2) = wv;   // words (Ic*4+2dh), (+1)
        }
    }
}

// ---------------------------------------------------------------------------
// Main. R15 structure EXACTLY (f16 chain, grid 4096, waves_per_eu(4,4), 52
// VGPR, absmax 0.25) with two surgical, bit-identical-value changes:
//  (1) X words come pre-packed from Xh as wave-uniform u32x4 loads feeding
//      the "s" constraint directly -- removes 16 pkrtz + 16 readfirstlane +
//      4 vector loads per f per wave.
//  (2) cross-f K prefetch: the jp=3 slot (previously load-free) issues
//      next-f's (jp=0) K words, which land during the MFMA phase instead of
//      stalling the next A-phase. Same addresses, earlier issue. +8 VGPR
//      live across MFMA phase (52 -> ~60, under the 64 budget; R12 proved
//      busting it spills catastrophically -- WRITE_SIZE is the tripwire).
// Discriminators: absmax EXACTLY 0.25, main 41.8 -> ~35-38us, WRITE_SIZE
// ~1MB, VGPR <= 64, FETCH ~2700KB.
// ---------------------------------------------------------------------------
__global__ __launch_bounds__(128)
__attribute__((amdgpu_waves_per_eu(4, 4)))
void tr_main16(const unsigned* __restrict__ Xh,
               const unsigned* __restrict__ K3h,
               float* __restrict__ out) {
    const int tid  = threadIdx.x;
    const int w    = __builtin_amdgcn_readfirstlane(tid >> 6);  // wave id, SGPR
    const int lane = tid & 63;
    const int c    = lane & 15;
    const int q    = lane >> 4;
    const int u      = blockIdx.x & 63;               // u-minor (R3/R7-proven)
    const int bgroup = blockIdx.x >> 6;               // 0..63
    const int b0     = ((bgroup << 1) + w) * G;       // SGPR-computed

    __shared__ __attribute__((aligned(16))) char lds[2 * G * 2048];
    char* Nb0 = lds + w * (G * 2048);

    // identity B-frags for f=0: B[k=8q+j][n=c(+16)]; f16 1.0 = 0x3C00 exact
    f16x8 idf0, idf1;
#pragma unroll
    for (int jj = 0; jj < 8; ++jj) {
        idf0[jj] = (8 * q + jj == c) ? (_Float16)1.0f : (_Float16)0.0f;
        idf1[jj] = (8 * q + jj == 16 + c) ? (_Float16)1.0f : (_Float16)0.0f;
    }

    const unsigned* Kt = K3h + ((size_t)u << 14) + (q << 9) + (c << 2);
    const f32x4 z = {0.f, 0.f, 0.f, 0.f};

    // f=0 jp=0 K words, issued before the loop (prefetch seed)
    u32x4 s0 = *(const u32x4*)(Kt + 0);       // (f=0, jp=0, I=0)
    u32x4 s1 = *(const u32x4*)(Kt + 64);      // (f=0, jp=0, I=1)

#pragma unroll
    for (int f = 0; f < NF; ++f) {
        const unsigned* Kf = Kt + (f << 11);

        // ---- X broadcasts: wave-uniform pre-packed words (SGPR loads) ----
        u32x4 xdd[G];
#pragma unroll
        for (int g = 0; g < G; ++g)
            xdd[g] = *(const u32x4*)(Xh + ((b0 + g) << 5) + (f << 2));

        // ---- A-phase: jp-outer, g-inner; 1-deep staging prefetch that
        //      crosses the f boundary at jp=3 (lands during MFMA phase) ----
        u32x4 A0u[G], A1u[G];
#pragma unroll
        for (int jp = 0; jp < 4; ++jp) {
            u32x4 c0 = s0, c1 = s1;
            if (jp < 3) {
                const unsigned* pn = Kf + ((jp + 1) << 7);
                s0 = *(const u32x4*)(pn + 0);
                s1 = *(const u32x4*)(pn + 64);
            } else if (f < NF - 1) {
                const unsigned* pn = Kf + 2048;   // next f, jp=0
                s0 = *(const u32x4*)(pn + 0);
                s1 = *(const u32x4*)(pn + 64);
            }
#pragma unroll
            for (int g = 0; g < G; ++g) {
                {   // I = 0: A-word = (T[e_par0], T[e_par1]) f16
                    unsigned tv = pkmul_h(c0[0], xdd[g][0]);
                    tv = pkfma_h(c0[1], xdd[g][1], tv);
                    tv = pkfma_h(c0[2], xdd[g][2], tv);
                    tv = pkfma_h(c0[3], xdd[g][3], tv);
                    A0u[g][jp] = tv;
                }
                {   // I = 1
                    unsigned tv = pkmul_h(c1[0], xdd[g][0]);
                    tv = pkfma_h(c1[1], xdd[g][1], tv);
                    tv = pkfma_h(c1[2], xdd[g][2], tv);
                    tv = pkfma_h(c1[3], xdd[g][3], tv);
                    A1u[g][jp] = tv;
                }
            }
        }

        // ---- MFMA phase per g (UNCHANGED R14/R15) ----
#pragma unroll
        for (int g = 0; g < G; ++g) {
            char* nb = Nb0 + (g << 11);
            f16x8 A0 = __builtin_bit_cast(f16x8, A0u[g]);
            f16x8 A1 = __builtin_bit_cast(f16x8, A1u[g]);

            f16x8 bf0, bf1;
            if (f == 0) { bf0 = idf0; bf1 = idf1; }
            else {
                bf0 = *(const f16x8*)(nb + (((q << 5) | c) << 4));
                bf1 = *(const f16x8*)(nb + (((q << 5) | c) << 4) + 256);
            }

            if (f < NF - 1) {
                f32x4 c00 = __builtin_amdgcn_mfma_f32_16x16x32_f16(A0, bf0, z, 0, 0, 0);
                f32x4 c01 = __builtin_amdgcn_mfma_f32_16x16x32_f16(A0, bf1, z, 0, 0, 0);
                f32x4 c10 = __builtin_amdgcn_mfma_f32_16x16x32_f16(A1, bf0, z, 0, 0, 0);
                f32x4 c11 = __builtin_amdgcn_mfma_f32_16x16x32_f16(A1, bf1, z, 0, 0, 0);
                // writeback N' (f16) for next f
#pragma unroll
                for (int I = 0; I < 2; ++I)
#pragma unroll
                    for (int J = 0; J < 2; ++J) {
                        f32x4 a = (I == 0) ? (J == 0 ? c00 : c01)
                                           : (J == 0 ? c10 : c11);
                        unsigned lo = pkrtz(a[0], a[1]);
                        unsigned hi = pkrtz(a[2], a[3]);
                        uint2 val; val.x = lo; val.y = hi;
                        // slot(p = 2I + (q>>1), n = 16J + c), byte +8*(q&1)
                        *(uint2*)(nb + (((((I << 1) | (q >> 1)) << 5) | (J << 4) | c) << 4)
                                     + ((q & 1) << 3)) = val;
                    }
            } else {
                // last step: only diagonal tiles feed the trace
                f32x4 c00 = __builtin_amdgcn_mfma_f32_16x16x32_f16(A0, bf0, z, 0, 0, 0);
                f32x4 c11 = __builtin_amdgcn_mfma_f32_16x16x32_f16(A1, bf1, z, 0, 0, 0);
                f32x4 t4 = c00 + c11;
                int ri = c & 3;
                float s = (ri == 0) ? t4[0] : (ri == 1) ? t4[1]
                        : (ri == 2) ? t4[2] : t4[3];
                s = ((c >> 2) == q) ? s : 0.f;
#pragma unroll
                for (int m = 32; m >= 1; m >>= 1) s += __shfl_xor(s, m, 64);
                if (lane == 0) out[((b0 + g) << 6) + u] = s;
            }
        }
        // Compiler memory fence: this-f LDS writes must precede next-f LDS
        // reads in program order (HW DS pipe is in-order per wave; only the
        // compiler could break it). Zero instructions emitted. Note: the
        // cross-f K prefetch was issued BEFORE this fence by design.
        asm volatile("" ::: "memory");
    }
}

extern "C" void kernel_launch(void* const* d_in, const int* in_sizes, int n_in,
                              void* d_out, int out_size, void* d_ws, size_t ws_size,
                              hipStream_t stream) {
    (void)in_sizes; (void)n_in; (void)out_size; (void)ws_size;
    const float* X = (const float*)d_in[0];   // [512][8][4]
    const float* K = (const float*)d_in[1];   // [4][32][32][8][64]
    float* out = (float*)d_out;               // [512][64]
    unsigned* K3h = (unsigned*)d_ws;                          // 4 MB
    unsigned* Xh  = (unsigned*)((char*)d_ws + (4u << 20));    // 64 KB

    hipLaunchKernelGGL(tr_k3h16, dim3(516), dim3(256), 0, stream, K, X, K3h, Xh);
    hipLaunchKernelGGL(tr_main16, dim3(4096), dim3(128), 0, stream, Xh, K3h, out);
}